// Round 3
// baseline (184.707 us; speedup 1.0000x reference)
//
#include <hip/hip_runtime.h>
#include <stdint.h>

// ---------------------------------------------------------------------------
// CommNetActor fused forward v3 — bf16x3 split-precision MFMA (gfx950).
//
//  - 4096 blocks x 128 thr (2 waves); block owns 64 rows (16 batches).
//  - Wave w owns output cols w*64..w*64+63 (2 nb blocks) x all 64 rows:
//    A-read duplication x2 (was x4), B fetched exactly once per block.
//  - LDS exactly 40960 B (Xhi 16K + Xlo 16K + 8K shared buf) -> 4 blocks/CU:
//    four independent blocks cover each other's barrier/L2 stalls.
//  - Shared 8K buf reused sequentially: S (16x128 hi/lo bf16) -> T (16x128
//    f32) -> dec partials P. S uses 16 rows only via MFMA garbage-row trick
//    (A row = lr&15; D rows 16..31 unused).
//  - Splits: hi = round-nearest bf16, lo = truncated bf16 of residual.
//  - cl4 refactor: H_cat@W = H3@(Wtop-0.25*Wbot) + S@(0.25*Wbot) = X@W1 + T.
//  - MFMA 32x32x16_bf16, D layout col=lane&31, row=(r&3)+8*(r>>2)+4*(lane>>5).
// ---------------------------------------------------------------------------

typedef __attribute__((ext_vector_type(4)))  float f32x4;
typedef __attribute__((ext_vector_type(16))) float f32x16;
typedef __attribute__((ext_vector_type(8)))  short bf16x8;
typedef __attribute__((ext_vector_type(4)))  short bf16x4;

#define WS_HALF 106496
#define SEG_ENC 0
#define SEG_FC1 8192
#define SEG_FC2 24576
#define SEG_FC3 40960
#define SEG_W1  57344
#define SEG_W2  73728
#define SEG_DEC 90112

#define MFMA(a, b, c) __builtin_amdgcn_mfma_f32_32x32x16_bf16((a), (b), (c), 0, 0, 0)

__device__ __forceinline__ unsigned short bf16_rn(float f) {
  union { float f; uint32_t u; } v; v.f = f;
  uint32_t u = v.u;
  return (unsigned short)((u + 0x7FFFu + ((u >> 16) & 1u)) >> 16);
}
__device__ __forceinline__ float bf16_f32(unsigned short h) {
  union { uint32_t u; float f; } v; v.u = ((uint32_t)h) << 16;
  return v.f;
}
// hi = round-nearest bf16; lo = TRUNCATED bf16 of residual (residual of the
// pair still ~2^-17 relative; saves VALU vs double-rn).
__device__ __forceinline__ void split_hl(float v, short& h, short& l) {
  unsigned short hh = bf16_rn(v);
  h = (short)hh;
  union { float f; uint32_t u; } c; c.f = v - bf16_f32(hh);
  l = (short)(c.u >> 16);
}
__device__ __forceinline__ f32x16 zero16() {
  f32x16 v;
#pragma unroll
  for (int i = 0; i < 16; ++i) v[i] = 0.0f;
  return v;
}
// swizzled bf16 index: pitch 128, 16B groups XOR'd by row&15
__device__ __forceinline__ int xswz(int row, int g) {
  return row * 128 + ((g ^ (row & 15)) << 3);
}
// barrier draining LDS only — register-bound global loads stay in flight
__device__ __forceinline__ void barrier_lds() {
  asm volatile("s_waitcnt lgkmcnt(0)\n\ts_barrier" ::: "memory");
}

// ---------------------------------------------------------------------------
// Weight prep (unchanged layout from v2): fragment f = kc*nbN + nb,
//   value = W[kc*16 + (lane>>5)*8 + j][nb*32 + (lane&31)]
// cl4 split into W1 = Wtop - 0.25*Wbot and W2 = 0.25*Wbot. dec padded N16->32.
// ---------------------------------------------------------------------------
__global__ void prep_weights(const float* __restrict__ enc_w, const float* __restrict__ fc1_w,
                             const float* __restrict__ fc2_w, const float* __restrict__ fc3_w,
                             const float* __restrict__ cl4_w, const float* __restrict__ dec_w,
                             unsigned short* __restrict__ ws) {
  int idx = blockIdx.x * 256 + threadIdx.x;
  if (idx >= WS_HALF) return;
  const float* W; int base, N, nbN, mode;
  if      (idx <  8192) { W = enc_w; base = SEG_ENC; N = 128; nbN = 4; mode = 0; }
  else if (idx < 24576) { W = fc1_w; base = SEG_FC1; N = 128; nbN = 4; mode = 0; }
  else if (idx < 40960) { W = fc2_w; base = SEG_FC2; N = 128; nbN = 4; mode = 0; }
  else if (idx < 57344) { W = fc3_w; base = SEG_FC3; N = 128; nbN = 4; mode = 0; }
  else if (idx < 73728) { W = cl4_w; base = SEG_W1;  N = 128; nbN = 4; mode = 1; }
  else if (idx < 90112) { W = cl4_w; base = SEG_W2;  N = 128; nbN = 4; mode = 2; }
  else                  { W = dec_w; base = SEG_DEC; N = 16;  nbN = 1; mode = 0; }
  int local = idx - base;
  int j    = local & 7;
  int lane = (local >> 3) & 63;
  int frag = local >> 9;
  int nb = frag % nbN;
  int kc = frag / nbN;
  int k = kc * 16 + ((lane >> 5) << 3) + j;
  int n = nb * 32 + (lane & 31);
  float wv;
  if (mode == 0)      wv = (n < N) ? W[k * N + n] : 0.0f;
  else if (mode == 1) wv = W[k * 128 + n] - 0.25f * W[(k + 128) * 128 + n];
  else                wv = 0.25f * W[(k + 128) * 128 + n];
  unsigned short hi = bf16_rn(wv);
  ws[idx]           = hi;
  ws[WS_HALF + idx] = bf16_rn(wv - bf16_f32(hi));
}

// ---------------------------------------------------------------------------
// Standard layer: X[64][K] @ W[K][128] (+T) + b, act, in-place into Xhi/Xlo.
// Wave w: cols w*64..+63 (nb=0,1), rows 0..63 (mb=0,1). B double-buffered
// from global one kc ahead. 12 MFMAs per kc (3 split terms x 2mb x 2nb).
// ---------------------------------------------------------------------------
template <int KC, int ACT, bool ADDT>
__device__ __forceinline__ void layer_std(short* __restrict__ Xhi, short* __restrict__ Xlo,
                                          const unsigned short* __restrict__ whi,
                                          const unsigned short* __restrict__ wlo,
                                          const float* __restrict__ bias,
                                          const float* __restrict__ Tf, int tid) {
  const int l = tid & 63, w = tid >> 6;
  const int lr = l & 31, lh = l >> 5;
  f32x16 acc00 = zero16(), acc01 = zero16(), acc10 = zero16(), acc11 = zero16();
  const unsigned short* bh0 = whi + (w * 2 + 0) * 512 + l * 8;
  const unsigned short* bh1 = whi + (w * 2 + 1) * 512 + l * 8;
  const unsigned short* bl0 = wlo + (w * 2 + 0) * 512 + l * 8;
  const unsigned short* bl1 = wlo + (w * 2 + 1) * 512 + l * 8;
  bf16x8 Bh0[2], Bh1[2], Bl0[2], Bl1[2];
  Bh0[0] = *(const bf16x8*)bh0;  Bh1[0] = *(const bf16x8*)bh1;
  Bl0[0] = *(const bf16x8*)bl0;  Bl1[0] = *(const bf16x8*)bl1;
  barrier_lds();   // X from previous phase visible
#pragma unroll
  for (int kc = 0; kc < KC; ++kc) {
    const int cur = kc & 1, nxt = cur ^ 1;
    if (kc + 1 < KC) {
      Bh0[nxt] = *(const bf16x8*)(bh0 + (kc + 1) * 2048);
      Bh1[nxt] = *(const bf16x8*)(bh1 + (kc + 1) * 2048);
      Bl0[nxt] = *(const bf16x8*)(bl0 + (kc + 1) * 2048);
      Bl1[nxt] = *(const bf16x8*)(bl1 + (kc + 1) * 2048);
    }
    const int g = kc * 2 + lh;
    const int xi0 = xswz(lr, g), xi1 = xswz(lr + 32, g);
    const bf16x8 ah0 = *(const bf16x8*)&Xhi[xi0];
    const bf16x8 al0 = *(const bf16x8*)&Xlo[xi0];
    const bf16x8 ah1 = *(const bf16x8*)&Xhi[xi1];
    const bf16x8 al1 = *(const bf16x8*)&Xlo[xi1];
    acc00 = MFMA(ah0, Bh0[cur], acc00);
    acc10 = MFMA(ah1, Bh0[cur], acc10);
    acc01 = MFMA(ah0, Bh1[cur], acc01);
    acc11 = MFMA(ah1, Bh1[cur], acc11);
    acc00 = MFMA(al0, Bh0[cur], acc00);
    acc10 = MFMA(al1, Bh0[cur], acc10);
    acc01 = MFMA(al0, Bh1[cur], acc01);
    acc11 = MFMA(al1, Bh1[cur], acc11);
    acc00 = MFMA(ah0, Bl0[cur], acc00);
    acc10 = MFMA(ah1, Bl0[cur], acc10);
    acc01 = MFMA(ah0, Bl1[cur], acc01);
    acc11 = MFMA(ah1, Bl1[cur], acc11);
  }
  barrier_lds();   // all waves done reading X -> in-place write safe
#pragma unroll
  for (int nb = 0; nb < 2; ++nb) {
    const int col = w * 64 + nb * 32 + lr;
    const float bv = ADDT ? 0.0f : bias[col];   // cl4 bias folded into T
    const int cg = col >> 3, co = col & 7;
#pragma unroll
    for (int mb = 0; mb < 2; ++mb) {
      const f32x16 a = nb ? (mb ? acc11 : acc01) : (mb ? acc10 : acc00);
#pragma unroll
      for (int r = 0; r < 16; ++r) {
        const int orow = mb * 32 + (r & 3) + 8 * (r >> 2) + 4 * lh;
        float v = a[r] + bv;
        if (ADDT) v += Tf[(orow >> 2) * 128 + col];
        if (ACT == 0)      v = 1.0f / (1.0f + __expf(-v));  // sigmoid
        else if (ACT == 1) v = fmaxf(v, 0.0f);              // relu
        short h, lo2;
        split_hl(v, h, lo2);
        const int idx = orow * 128 + ((cg ^ (orow & 15)) << 3) + co;
        Xhi[idx] = h;
        Xlo[idx] = lo2;
      }
    }
  }
}

// ---------------------------------------------------------------------------
__global__ __launch_bounds__(128, 2)
void commnet_fwd(const float* __restrict__ O,
                 const float* __restrict__ enc_b, const float* __restrict__ fc1_b,
                 const float* __restrict__ fc2_b, const float* __restrict__ fc3_b,
                 const float* __restrict__ cl4_b, const float* __restrict__ dec_b,
                 const unsigned short* __restrict__ ws, float* __restrict__ out) {
  __shared__ __attribute__((aligned(16))) short Xhi[64 * 128];  // 16 KB
  __shared__ __attribute__((aligned(16))) short Xlo[64 * 128];  // 16 KB
  __shared__ __attribute__((aligned(16))) float buf[2048];      //  8 KB: S -> T -> P

  const int tid = threadIdx.x;
  const int l = tid & 63, w = tid >> 6;
  const int lr = l & 31, lh = l >> 5;

  // ---- stage O [64 x 64] f32 -> split -> swizzled Xhi/Xlo groups 0..7 ----
  {
    const f32x4* Og = (const f32x4*)(O + (long)blockIdx.x * 4096);
#pragma unroll
    for (int it = 0; it < 8; ++it) {
      const int i = it * 128 + tid;       // 0..1023
      const int row = i >> 4;
      const int c4 = (i & 15) << 2;
      f32x4 v = Og[i];
      bf16x4 hv, lv;
#pragma unroll
      for (int j = 0; j < 4; ++j) {
        short hh, ll;
        split_hl(v[j], hh, ll);
        hv[j] = hh; lv[j] = ll;
      }
      const int bi = row * 128 + (((c4 >> 3) ^ (row & 15)) << 3) + (c4 & 7);
      *(bf16x4*)&Xhi[bi] = hv;
      *(bf16x4*)&Xlo[bi] = lv;
    }
  }

  const unsigned short* whi = ws;
  const unsigned short* wlo = ws + WS_HALF;
  short* Shi = (short*)buf;          // 16 x 128 bf16 hi  (4 KB)
  short* Slo = Shi + 2048;           // 16 x 128 bf16 lo  (4 KB)

  layer_std<4, 0, false>(Xhi, Xlo, whi + SEG_ENC, wlo + SEG_ENC, enc_b, buf, tid);
  layer_std<8, 1, false>(Xhi, Xlo, whi + SEG_FC1, wlo + SEG_FC1, fc1_b, buf, tid);
  layer_std<8, 1, false>(Xhi, Xlo, whi + SEG_FC2, wlo + SEG_FC2, fc2_b, buf, tid);
  layer_std<8, 1, false>(Xhi, Xlo, whi + SEG_FC3, wlo + SEG_FC3, fc3_b, fc3_b, tid);

  barrier_lds();   // fc3 output visible
  // ---- comm: S[b] = sum of 4 agents' H3 rows (16 rows only) ----
  {
    const int b = tid >> 3, g0 = tid & 7;
#pragma unroll
    for (int half = 0; half < 2; ++half) {
      const int g = g0 + half * 8;
      float s[8];
#pragma unroll
      for (int j = 0; j < 8; ++j) s[j] = 0.0f;
#pragma unroll
      for (int a = 0; a < 4; ++a) {
        const int xi = xswz(b * 4 + a, g);
        const bf16x8 hh = *(const bf16x8*)&Xhi[xi];
        const bf16x8 ll = *(const bf16x8*)&Xlo[xi];
#pragma unroll
        for (int j = 0; j < 8; ++j)
          s[j] += bf16_f32((unsigned short)hh[j]) + bf16_f32((unsigned short)ll[j]);
      }
      bf16x8 sh, sl;
#pragma unroll
      for (int j = 0; j < 8; ++j) {
        short h2, l2; split_hl(s[j], h2, l2);
        sh[j] = h2; sl[j] = l2;
      }
      const int si = b * 128 + ((g ^ b) << 3);
      *(bf16x8*)&Shi[si] = sh;
      *(bf16x8*)&Slo[si] = sl;
    }
  }
  barrier_lds();   // S visible

  // ---- tgemm: T = S @ W2 + cl4_b  (A rows = lr&15 dup; D rows 16..31 junk) ----
  {
    const int rowA = lr & 15;
    f32x16 t0 = zero16(), t1 = zero16();
    const unsigned short* bh0 = whi + SEG_W2 + (w * 2 + 0) * 512 + l * 8;
    const unsigned short* bh1 = whi + SEG_W2 + (w * 2 + 1) * 512 + l * 8;
    const unsigned short* bl0 = wlo + SEG_W2 + (w * 2 + 0) * 512 + l * 8;
    const unsigned short* bl1 = wlo + SEG_W2 + (w * 2 + 1) * 512 + l * 8;
    bf16x8 Bh0[2], Bh1[2], Bl0[2], Bl1[2];
    Bh0[0] = *(const bf16x8*)bh0;  Bh1[0] = *(const bf16x8*)bh1;
    Bl0[0] = *(const bf16x8*)bl0;  Bl1[0] = *(const bf16x8*)bl1;
#pragma unroll
    for (int kc = 0; kc < 8; ++kc) {
      const int cur = kc & 1, nxt = cur ^ 1;
      if (kc < 7) {
        Bh0[nxt] = *(const bf16x8*)(bh0 + (kc + 1) * 2048);
        Bh1[nxt] = *(const bf16x8*)(bh1 + (kc + 1) * 2048);
        Bl0[nxt] = *(const bf16x8*)(bl0 + (kc + 1) * 2048);
        Bl1[nxt] = *(const bf16x8*)(bl1 + (kc + 1) * 2048);
      }
      const int g = kc * 2 + lh;
      const int si = rowA * 128 + ((g ^ rowA) << 3);
      const bf16x8 sh = *(const bf16x8*)&Shi[si];
      const bf16x8 sl = *(const bf16x8*)&Slo[si];
      t0 = MFMA(sh, Bh0[cur], t0);
      t1 = MFMA(sh, Bh1[cur], t1);
      t0 = MFMA(sl, Bh0[cur], t0);
      t1 = MFMA(sl, Bh1[cur], t1);
      t0 = MFMA(sh, Bl0[cur], t0);
      t1 = MFMA(sh, Bl1[cur], t1);
    }
    barrier_lds();   // all S reads complete -> overwrite buf with T
#pragma unroll
    for (int nb = 0; nb < 2; ++nb) {
      const int col = w * 64 + nb * 32 + lr;
      const float bv = cl4_b[col];
#pragma unroll
      for (int r = 0; r < 8; ++r) {   // D rows 0..15 only
        const int prow = (r & 3) + 8 * (r >> 2) + 4 * lh;
        buf[prow * 128 + col] = (nb ? t1[r] : t0[r]) + bv;
      }
    }
  }

  // cl4: H4 = H3 @ W1 + T  (no activation); entry barrier orders T writes
  layer_std<8, 2, true>(Xhi, Xlo, whi + SEG_W1, wlo + SEG_W1, cl4_b, buf, tid);

  barrier_lds();   // H4 in X visible; T reads done -> buf reusable as P

  // ---- dec: [16 x 512] @ dec_w(pad32); K halves across the 2 waves ----
  {
    f32x16 dacc = zero16();
    const unsigned short* bh = whi + SEG_DEC + (w * 16) * 512 + l * 8;
    const unsigned short* bl = wlo + SEG_DEC + (w * 16) * 512 + l * 8;
    bf16x8 Bh[2], Bl[2];
    Bh[0] = *(const bf16x8*)bh;
    Bl[0] = *(const bf16x8*)bl;
#pragma unroll
    for (int k8 = 0; k8 < 16; ++k8) {
      const int cur = k8 & 1, nxt = cur ^ 1;
      if (k8 < 15) {
        Bh[nxt] = *(const bf16x8*)(bh + (k8 + 1) * 512);
        Bl[nxt] = *(const bf16x8*)(bl + (k8 + 1) * 512);
      }
      const int kg = (w * 16 + k8) * 2 + lh;   // k/8 in 0..63
      const int agent = kg >> 4;
      const int gc = kg & 15;
      const int xr = (lr & 15) * 4 + agent;    // batch*4 + agent (rows dup'd)
      const int xi = xr * 128 + ((gc ^ (xr & 15)) << 3);
      const bf16x8 ah = *(const bf16x8*)&Xhi[xi];
      const bf16x8 al = *(const bf16x8*)&Xlo[xi];
      dacc = MFMA(ah, Bh[cur], dacc);
      dacc = MFMA(al, Bh[cur], dacc);
      dacc = MFMA(ah, Bl[cur], dacc);
    }
    if (lr < 16) {
#pragma unroll
      for (int r = 0; r < 8; ++r) {
        const int prow = (r & 3) + 8 * (r >> 2) + 4 * lh;
        buf[w * 272 + prow * 17 + lr] = dacc[r];
      }
    }
  }
  barrier_lds();   // P visible

  // ---- reduce 2 partials + bias, softmax over 16 cols, store ----
  {
    const int c = tid & 15, bb = tid >> 4;   // bb 0..7
#pragma unroll
    for (int half = 0; half < 2; ++half) {
      const int b = bb + half * 8;
      float v = buf[b * 17 + c] + buf[272 + b * 17 + c] + dec_b[c];
      float m = v;
#pragma unroll
      for (int mk = 1; mk < 16; mk <<= 1) m = fmaxf(m, __shfl_xor(m, mk, 16));
      const float e = __expf(v - m);
      float sum2 = e;
#pragma unroll
      for (int mk = 1; mk < 16; mk <<= 1) sum2 += __shfl_xor(sum2, mk, 16);
      out[(long)blockIdx.x * 256 + b * 16 + c] = e / sum2;
    }
  }
}

// ---------------------------------------------------------------------------
extern "C" void kernel_launch(void* const* d_in, const int* in_sizes, int n_in,
                              void* d_out, int out_size, void* d_ws, size_t ws_size,
                              hipStream_t stream) {
  (void)n_in; (void)out_size; (void)ws_size;  // needs ws_size >= 425,984 B
  const float* O     = (const float*)d_in[0];
  const float* enc_w = (const float*)d_in[1];
  const float* enc_b = (const float*)d_in[2];
  const float* fc1_w = (const float*)d_in[3];
  const float* fc1_b = (const float*)d_in[4];
  const float* fc2_w = (const float*)d_in[5];
  const float* fc2_b = (const float*)d_in[6];
  const float* fc3_w = (const float*)d_in[7];
  const float* fc3_b = (const float*)d_in[8];
  const float* cl4_w = (const float*)d_in[9];
  const float* cl4_b = (const float*)d_in[10];
  const float* dec_w = (const float*)d_in[11];
  const float* dec_b = (const float*)d_in[12];
  unsigned short* wsb = (unsigned short*)d_ws;

  prep_weights<<<(WS_HALF + 255) / 256, 256, 0, stream>>>(enc_w, fc1_w, fc2_w, fc3_w,
                                                          cl4_w, dec_w, wsb);
  const int rows   = in_sizes[0] / 64;   // B*A = 262144
  const int blocks = rows / 64;          // 4096
  commnet_fwd<<<blocks, 128, 0, stream>>>(O, enc_b, fc1_b, fc2_b, fc3_b, cl4_b,
                                          dec_b, wsb, (float*)d_out);
}